// Round 1
// 828.898 us; speedup vs baseline: 1.0930x; 1.0930x over previous
//
#include <hip/hip_runtime.h>

// Problem constants (B=1)
#define DM    256
#define NHD   4
#define HD    64
#define NSEQ  768
#define MSEQ  768

// workspace layout (floats)
#define WS_Q  0
#define WS_K  196608
#define WS_V  393216
#define WS_U  589824   // 768*1024 floats

// native vector type for nontemporal builtins (HIP float4 is a class -> rejected)
typedef float nativef4 __attribute__((ext_vector_type(4)));

// ---------------- DPP helpers (VALU-pipe cross-lane, avoids LDS pipe) ----------------
template<int CTRL, bool BC>
static __device__ __forceinline__ float dpp_mov_f(float x) {
    int xi = __float_as_int(x);
    int r = __builtin_amdgcn_update_dpp(BC ? 0 : xi, xi, CTRL, 0xF, 0xF, BC);
    return __int_as_float(r);
}
// sum within rows of 16; lane (16r+15) holds row r sum
static __device__ __forceinline__ float row16_sum(float x) {
    x += dpp_mov_f<0x111, true>(x);  // row_shr:1
    x += dpp_mov_f<0x112, true>(x);  // row_shr:2
    x += dpp_mov_f<0x114, true>(x);  // row_shr:4
    x += dpp_mov_f<0x118, true>(x);  // row_shr:8
    return x;
}
// full 64-lane sum -> lane 63
static __device__ __forceinline__ float wave_sum(float x) {
    x = row16_sum(x);
    x += dpp_mov_f<0x142, true>(x);  // row_bcast:15
    x += dpp_mov_f<0x143, true>(x);  // row_bcast:31
    return x;
}
// full 64-lane max -> lane 63
static __device__ __forceinline__ float wave_max(float x) {
    x = fmaxf(x, dpp_mov_f<0x111, false>(x));
    x = fmaxf(x, dpp_mov_f<0x112, false>(x));
    x = fmaxf(x, dpp_mov_f<0x114, false>(x));
    x = fmaxf(x, dpp_mov_f<0x118, false>(x));
    x = fmaxf(x, dpp_mov_f<0x142, false>(x));
    x = fmaxf(x, dpp_mov_f<0x143, false>(x));
    return x;
}

// ---------------- Kernel 1: q/k/v projections  C = X @ W^T + b ----------------
// grid (12, 4, 3), block 256.  64x64 tile, 4x4 microtile, K staged in 64-chunks,
// both operands transposed into LDS (stride 68 keeps b128 alignment, ~2-way banks).
__global__ __launch_bounds__(256) void proj_nt_kernel(
    const float* __restrict__ Xq, const float* __restrict__ Xk, const float* __restrict__ Xv,
    const float* __restrict__ Wq, const float* __restrict__ Wk, const float* __restrict__ Wv,
    const float* __restrict__ bq, const float* __restrict__ bk, const float* __restrict__ bv,
    float* __restrict__ ws)
{
    const int z = blockIdx.z;
    const float* X    = (z == 0) ? Xq : (z == 1) ? Xk : Xv;
    const float* W    = (z == 0) ? Wq : (z == 1) ? Wk : Wv;
    const float* bias = (z == 0) ? bq : (z == 1) ? bk : bv;
    float* C = ws + (size_t)z * (NSEQ * DM);

    const int n0 = blockIdx.x * 64;
    const int j0 = blockIdx.y * 64;
    const int t  = threadIdx.x;
    const int ar  = t & 63;
    const int seg = (t >> 6) << 4;     // 0,16,32,48
    const int tr  = t >> 4;            // 0..15
    const int tc  = t & 15;            // 0..15

    __shared__ float Al[64 * 68];
    __shared__ float Bl[64 * 68];

    float acc[4][4] = {};

    for (int kc = 0; kc < 4; ++kc) {
        const int k0 = kc * 64;
        // stage A (transpose): Al[k][n]
        {
            const float4* s4 = (const float4*)(X + (size_t)(n0 + ar) * DM + k0 + seg);
            float tmp[16];
            *(float4*)&tmp[0]  = s4[0]; *(float4*)&tmp[4]  = s4[1];
            *(float4*)&tmp[8]  = s4[2]; *(float4*)&tmp[12] = s4[3];
            #pragma unroll
            for (int w2 = 0; w2 < 16; ++w2) Al[(seg + w2) * 68 + ar] = tmp[w2];
        }
        // stage B (transpose): Bl[k][j]
        {
            const float4* s4 = (const float4*)(W + (size_t)(j0 + ar) * DM + k0 + seg);
            float tmp[16];
            *(float4*)&tmp[0]  = s4[0]; *(float4*)&tmp[4]  = s4[1];
            *(float4*)&tmp[8]  = s4[2]; *(float4*)&tmp[12] = s4[3];
            #pragma unroll
            for (int w2 = 0; w2 < 16; ++w2) Bl[(seg + w2) * 68 + ar] = tmp[w2];
        }
        __syncthreads();
        #pragma unroll 8
        for (int kk = 0; kk < 64; ++kk) {
            float4 a = *(const float4*)&Al[kk * 68 + tr * 4];
            float4 b = *(const float4*)&Bl[kk * 68 + tc * 4];
            acc[0][0] = fmaf(a.x, b.x, acc[0][0]); acc[0][1] = fmaf(a.x, b.y, acc[0][1]);
            acc[0][2] = fmaf(a.x, b.z, acc[0][2]); acc[0][3] = fmaf(a.x, b.w, acc[0][3]);
            acc[1][0] = fmaf(a.y, b.x, acc[1][0]); acc[1][1] = fmaf(a.y, b.y, acc[1][1]);
            acc[1][2] = fmaf(a.y, b.z, acc[1][2]); acc[1][3] = fmaf(a.y, b.w, acc[1][3]);
            acc[2][0] = fmaf(a.z, b.x, acc[2][0]); acc[2][1] = fmaf(a.z, b.y, acc[2][1]);
            acc[2][2] = fmaf(a.z, b.z, acc[2][2]); acc[2][3] = fmaf(a.z, b.w, acc[2][3]);
            acc[3][0] = fmaf(a.w, b.x, acc[3][0]); acc[3][1] = fmaf(a.w, b.y, acc[3][1]);
            acc[3][2] = fmaf(a.w, b.z, acc[3][2]); acc[3][3] = fmaf(a.w, b.w, acc[3][3]);
        }
        __syncthreads();
    }

    const float b0 = bias[j0 + tc * 4 + 0];
    const float b1 = bias[j0 + tc * 4 + 1];
    const float b2 = bias[j0 + tc * 4 + 2];
    const float b3 = bias[j0 + tc * 4 + 3];
    #pragma unroll
    for (int i = 0; i < 4; ++i) {
        float4 o;
        o.x = acc[i][0] + b0; o.y = acc[i][1] + b1;
        o.z = acc[i][2] + b2; o.w = acc[i][3] + b3;
        *(float4*)(C + (size_t)(n0 + tr * 4 + i) * DM + j0 + tc * 4) = o;
    }
}

// ---------------- Kernel 2: u[n][h][d] = sum_c qproj[n][h*64+c] * Wp[h*64+c][d] ----------------
// grid (12, 4, 4=h), block 256.  K=64 single chunk.
__global__ __launch_bounds__(256) void u_nn_kernel(
    const float* __restrict__ qproj, const float* __restrict__ Wp, float* __restrict__ U)
{
    const int h  = blockIdx.z;
    const int n0 = blockIdx.x * 64;
    const int d0 = blockIdx.y * 64;
    const int t  = threadIdx.x;

    __shared__ float Al[64 * 68];  // Al[c][n]
    __shared__ float Bl[64 * 68];  // Bl[c][d]

    // stage A (transpose)
    {
        const int ar = t & 63, seg = (t >> 6) << 4;
        const float4* s4 = (const float4*)(qproj + (size_t)(n0 + ar) * DM + h * HD + seg);
        float tmp[16];
        *(float4*)&tmp[0]  = s4[0]; *(float4*)&tmp[4]  = s4[1];
        *(float4*)&tmp[8]  = s4[2]; *(float4*)&tmp[12] = s4[3];
        #pragma unroll
        for (int w2 = 0; w2 < 16; ++w2) Al[(seg + w2) * 68 + ar] = tmp[w2];
    }
    // stage B (natural)
    {
        const int c = t >> 2, dseg = (t & 3) << 4;
        const float4* s4 = (const float4*)(Wp + (size_t)(h * HD + c) * DM + d0 + dseg);
        float4 v0 = s4[0], v1 = s4[1], v2 = s4[2], v3 = s4[3];
        *(float4*)&Bl[c * 68 + dseg + 0]  = v0;
        *(float4*)&Bl[c * 68 + dseg + 4]  = v1;
        *(float4*)&Bl[c * 68 + dseg + 8]  = v2;
        *(float4*)&Bl[c * 68 + dseg + 12] = v3;
    }
    __syncthreads();

    const int tr = t >> 4, tc = t & 15;
    float acc[4][4] = {};
    #pragma unroll 8
    for (int kk = 0; kk < 64; ++kk) {
        float4 a = *(const float4*)&Al[kk * 68 + tr * 4];
        float4 b = *(const float4*)&Bl[kk * 68 + tc * 4];
        acc[0][0] = fmaf(a.x, b.x, acc[0][0]); acc[0][1] = fmaf(a.x, b.y, acc[0][1]);
        acc[0][2] = fmaf(a.x, b.z, acc[0][2]); acc[0][3] = fmaf(a.x, b.w, acc[0][3]);
        acc[1][0] = fmaf(a.y, b.x, acc[1][0]); acc[1][1] = fmaf(a.y, b.y, acc[1][1]);
        acc[1][2] = fmaf(a.y, b.z, acc[1][2]); acc[1][3] = fmaf(a.y, b.w, acc[1][3]);
        acc[2][0] = fmaf(a.z, b.x, acc[2][0]); acc[2][1] = fmaf(a.z, b.y, acc[2][1]);
        acc[2][2] = fmaf(a.z, b.z, acc[2][2]); acc[2][3] = fmaf(a.z, b.w, acc[2][3]);
        acc[3][0] = fmaf(a.w, b.x, acc[3][0]); acc[3][1] = fmaf(a.w, b.y, acc[3][1]);
        acc[3][2] = fmaf(a.w, b.z, acc[3][2]); acc[3][3] = fmaf(a.w, b.w, acc[3][3]);
    }

    #pragma unroll
    for (int i = 0; i < 4; ++i) {
        float4 o; o.x = acc[i][0]; o.y = acc[i][1]; o.z = acc[i][2]; o.w = acc[i][3];
        *(float4*)(U + (size_t)(n0 + tr * 4 + i) * (NHD * DM) + h * DM + d0 + tc * 4) = o;
    }
}

// ---------------- Kernel 3: fused scores + softmax + attn@v ----------------
// grid 768 (n), block 768 (12 waves).
// Phase 1 rework: one instruction loads one FULL contiguous embed row (lane L holds
// floats [4L,4L+4)), so every fetched 64B line is consumed within a single
// instruction -> immune to nt no-allocate refetch, zero head duplication.
// Each lane keeps the matching 4-float strip of U[h] for all 4 heads (16 VGPRs).
__global__ __launch_bounds__(768, 6) void attn_main_kernel(
    const float* __restrict__ embed, const float* __restrict__ ws, float* __restrict__ out)
{
    const float* qproj = ws + WS_Q;
    const float* kproj = ws + WS_K;
    const float* vproj = ws + WS_V;
    const float* U     = ws + WS_U;

    const int n    = blockIdx.x;
    const int tid  = threadIdx.x;
    const int wid  = tid >> 6;
    const int lane = tid & 63;

    __shared__ float sc[4 * 776];        // scores / attn, stride 776 breaks bank aliasing
    __shared__ float part[12 * 256];     // attn@v partials
    __shared__ float redm[12], reds[12]; // cross-wave softmax reductions

    // ---- phase 1: scores (embed·u fold + q·k fold), full-row coalesced ----
    {
        const int c4 = lane << 2;           // this lane's 4-float strip [c4, c4+4)
        const int hl = lane >> 4;           // head owning this strip (for the q·k term)

        const float* Ub = U + (size_t)n * (NHD * DM);
        const float4 U0 = *(const float4*)(Ub + 0 * DM + c4);
        const float4 U1 = *(const float4*)(Ub + 1 * DM + c4);
        const float4 U2 = *(const float4*)(Ub + 2 * DM + c4);
        const float4 U3 = *(const float4*)(Ub + 3 * DM + c4);
        const float4 Q4 = *(const float4*)(qproj + (size_t)n * DM + c4);

        const size_t ebase = (size_t)n * MSEQ * DM + c4;
        #pragma unroll 4
        for (int i = 0; i < 64; ++i) {
            const int m = wid * 64 + i;
            nativef4 e = __builtin_nontemporal_load(
                (const nativef4*)(embed + ebase + (size_t)m * DM));
            float4 K4 = *(const float4*)(kproj + (size_t)m * DM + c4);

            float p0 = fmaf(e.x, U0.x, fmaf(e.y, U0.y, fmaf(e.z, U0.z, e.w * U0.w)));
            float p1 = fmaf(e.x, U1.x, fmaf(e.y, U1.y, fmaf(e.z, U1.z, e.w * U1.w)));
            float p2 = fmaf(e.x, U2.x, fmaf(e.y, U2.y, fmaf(e.z, U2.z, e.w * U2.w)));
            float p3 = fmaf(e.x, U3.x, fmaf(e.y, U3.y, fmaf(e.z, U3.z, e.w * U3.w)));
            float pk = fmaf(K4.x, Q4.x, fmaf(K4.y, Q4.y, fmaf(K4.z, Q4.z, K4.w * Q4.w)));
            p0 += (hl == 0) ? pk : 0.0f;
            p1 += (hl == 1) ? pk : 0.0f;
            p2 += (hl == 2) ? pk : 0.0f;
            p3 += (hl == 3) ? pk : 0.0f;
            p0 = wave_sum(p0);
            p1 = wave_sum(p1);
            p2 = wave_sum(p2);
            p3 = wave_sum(p3);
            if (lane == 63) {
                sc[0 * 776 + m] = p0;
                sc[1 * 776 + m] = p1;
                sc[2 * 776 + m] = p2;
                sc[3 * 776 + m] = p3;
            }
        }
    }
    __syncthreads();

    // ---- phase 2: softmax per (h) row; wave (h = wid&3, third = wid>>2) ----
    {
        const int h = wid & 3, third = wid >> 2;
        const int mm = third * 256 + (lane << 2);
        float4 p4 = *(const float4*)&sc[h * 776 + mm];
        const float v0 = p4.x * 0.125f, v1 = p4.y * 0.125f;
        const float v2 = p4.z * 0.125f, v3 = p4.w * 0.125f;

        float wmax = wave_max(fmaxf(fmaxf(v0, v1), fmaxf(v2, v3)));
        if (lane == 63) redm[wid] = wmax;
        __syncthreads();
        const float rmax = fmaxf(fmaxf(redm[h], redm[h + 4]), redm[h + 8]);

        const float x0 = __expf(v0 - rmax), x1 = __expf(v1 - rmax);
        const float x2 = __expf(v2 - rmax), x3 = __expf(v3 - rmax);
        float wsum = wave_sum((x0 + x1) + (x2 + x3));
        if (lane == 63) reds[wid] = wsum;
        __syncthreads();
        const float inv = 1.0f / (reds[h] + reds[h + 4] + reds[h + 8]);

        float4 a4;
        a4.x = x0 * inv; a4.y = x1 * inv; a4.z = x2 * inv; a4.w = x3 * inv;
        *(float4*)&sc[h * 776 + mm] = a4;

        nativef4 an = { a4.x, a4.y, a4.z, a4.w };
        float* aout = out + (size_t)NSEQ * DM + ((size_t)h * NSEQ + n) * MSEQ + mm;
        __builtin_nontemporal_store(an, (nativef4*)aout);
    }
    __syncthreads();

    // ---- phase 3: hidden[n] = attn @ v ----
    {
        const int g  = tid >> 6;            // m-group 0..11 (64 m each)
        const int jb = (tid & 63) << 2;     // output cols j..j+3
        const int h  = jb >> 6;
        const int mbase = g * 64;
        float4 acc = make_float4(0.f, 0.f, 0.f, 0.f);
        for (int mi = 0; mi < 64; mi += 4) {
            float4 a4 = *(const float4*)&sc[h * 776 + mbase + mi];
            float4 va = *(const float4*)(vproj + (size_t)(mbase + mi + 0) * DM + jb);
            float4 vb = *(const float4*)(vproj + (size_t)(mbase + mi + 1) * DM + jb);
            float4 vc = *(const float4*)(vproj + (size_t)(mbase + mi + 2) * DM + jb);
            float4 vd = *(const float4*)(vproj + (size_t)(mbase + mi + 3) * DM + jb);
            acc.x = fmaf(a4.x, va.x, acc.x); acc.y = fmaf(a4.x, va.y, acc.y);
            acc.z = fmaf(a4.x, va.z, acc.z); acc.w = fmaf(a4.x, va.w, acc.w);
            acc.x = fmaf(a4.y, vb.x, acc.x); acc.y = fmaf(a4.y, vb.y, acc.y);
            acc.z = fmaf(a4.y, vb.z, acc.z); acc.w = fmaf(a4.y, vb.w, acc.w);
            acc.x = fmaf(a4.z, vc.x, acc.x); acc.y = fmaf(a4.z, vc.y, acc.y);
            acc.z = fmaf(a4.z, vc.z, acc.z); acc.w = fmaf(a4.z, vc.w, acc.w);
            acc.x = fmaf(a4.w, vd.x, acc.x); acc.y = fmaf(a4.w, vd.y, acc.y);
            acc.z = fmaf(a4.w, vd.z, acc.z); acc.w = fmaf(a4.w, vd.w, acc.w);
        }
        *(float4*)&part[g * 256 + jb] = acc;
    }
    __syncthreads();
    if (tid < 256) {
        float s = 0.f;
        #pragma unroll
        for (int g = 0; g < 12; ++g) s += part[g * 256 + tid];
        out[(size_t)n * DM + tid] = s;
    }
}

extern "C" void kernel_launch(void* const* d_in, const int* in_sizes, int n_in,
                              void* d_out, int out_size, void* d_ws, size_t ws_size,
                              hipStream_t stream) {
    const float* input_q = (const float*)d_in[0];
    const float* input_k = (const float*)d_in[1];
    const float* input_v = (const float*)d_in[2];
    const float* embed   = (const float*)d_in[3];
    const float* Wq      = (const float*)d_in[4];
    const float* bq      = (const float*)d_in[5];
    const float* Wk      = (const float*)d_in[6];
    const float* bk      = (const float*)d_in[7];
    const float* Wv      = (const float*)d_in[8];
    const float* bv      = (const float*)d_in[9];
    const float* Wp      = (const float*)d_in[10];
    // d_in[11] = bp is intentionally unused: it is constant over m and cancels in softmax.

    float* ws  = (float*)d_ws;
    float* out = (float*)d_out;

    dim3 g1(12, 4, 3);
    proj_nt_kernel<<<g1, 256, 0, stream>>>(input_q, input_k, input_v,
                                           Wq, Wk, Wv, bq, bk, bv, ws);
    dim3 g2(12, 4, 4);
    u_nn_kernel<<<g2, 256, 0, stream>>>(ws + WS_Q, Wp, ws + WS_U);

    attn_main_kernel<<<768, 768, 0, stream>>>(embed, ws, out);
}